// Round 5
// baseline (231.009 us; speedup 1.0000x reference)
//
#include <hip/hip_runtime.h>
#include <hip/hip_bf16.h>

#define S_LEN 2048
#define NH    16
#define HD    64
#define HID   1024
#define BATCH 2
#define STK   72   // kt/vt LDS stride in shorts (144B rows, 16B aligned)
#define SCQ   0.18033688f   // 0.125 * log2(e), folded into q in gemm1 epilogue

typedef __bf16 bf16x8 __attribute__((ext_vector_type(8)));
typedef float  f32x4  __attribute__((ext_vector_type(4)));
typedef float  f32x16 __attribute__((ext_vector_type(16)));
typedef unsigned u32x2 __attribute__((ext_vector_type(2)));

__device__ __forceinline__ unsigned int pk2(float lo, float hi) {
    union { __hip_bfloat162 h; unsigned int u; } c;
    c.h = __float22bfloat162_rn(make_float2(lo, hi));   // v_cvt_pk_bf16_f32
    return c.u;
}
__device__ __forceinline__ uint4 pk8(float4 a, float4 b) {
    uint4 o;
    o.x = pk2(a.x, a.y); o.y = pk2(a.z, a.w);
    o.z = pk2(b.x, b.y); o.w = pk2(b.z, b.w);
    return o;
}
__device__ __forceinline__ float exp2_hw(float x) {
    float r; asm("v_exp_f32 %0, %1" : "=v"(r) : "v"(x)); return r;
}
// v_permlane32_swap_b32: vdst.hi32lanes <-> vsrc.lo32lanes.
// Returns {vdst', vsrc'}: for every lane, {r0,r1} = {own-half word, partner word}
// when called with the pair to exchange.
__device__ __forceinline__ void pl32swap(unsigned &a, unsigned &b) {
    u32x2 r = __builtin_amdgcn_permlane32_swap(a, b, false, false);
    a = r[0]; b = r[1];
}
// pair-combine helpers: swap(x,x) yields {own, partner} in some order per lane
__device__ __forceinline__ float pair_max(float x) {
    unsigned u = __float_as_uint(x);
    u32x2 r = __builtin_amdgcn_permlane32_swap(u, u, false, false);
    return fmaxf(__uint_as_float(r[0]), __uint_as_float(r[1]));
}
__device__ __forceinline__ float pair_sum(float x) {
    unsigned u = __float_as_uint(x);
    u32x2 r = __builtin_amdgcn_permlane32_swap(u, u, false, false);
    return __uint_as_float(r[0]) + __uint_as_float(r[1]);
}
__device__ __forceinline__ void gll16(const unsigned short* g, unsigned short* l) {
    __builtin_amdgcn_global_load_lds(
        (const __attribute__((address_space(1))) void*)g,
        (__attribute__((address_space(3))) void*)l, 16, 0, 0);
}

__global__ __launch_bounds__(256)
void fill_constf(float* __restrict__ out, long n, float v) {
    long i = (long)blockIdx.x * 256 + threadIdx.x;
    const long stride = (long)gridDim.x * 256;
    for (; i < n; i += stride) out[i] = v;
}

// fp32 -> bf16 bulk convert, 8 elems/iter.
__global__ __launch_bounds__(256)
void cvt_bf16(const float* __restrict__ src, unsigned short* __restrict__ dst, long n8) {
    long t = (long)blockIdx.x * 256 + threadIdx.x;
    const long stride = (long)gridDim.x * 256;
    for (; t < n8; t += stride) {
        const float4 a = *(const float4*)(src + t * 8);
        const float4 b = *(const float4*)(src + t * 8 + 4);
        *(uint4*)(dst + t * 8) = pk8(a, b);
    }
}
// two-tensor variant (x and qkv_w in one launch)
__global__ __launch_bounds__(256)
void cvt2_bf16(const float* __restrict__ s0, unsigned short* __restrict__ d0, long n0,
               const float* __restrict__ s1, unsigned short* __restrict__ d1, long n1) {
    long t = (long)blockIdx.x * 256 + threadIdx.x;
    const long stride = (long)gridDim.x * 256;
    for (; t < n0 + n1; t += stride) {
        const float* s; unsigned short* d; long i;
        if (t < n0) { s = s0; d = d0; i = t; } else { s = s1; d = d1; i = t - n0; }
        const float4 a = *(const float4*)(s + i * 8);
        const float4 b = *(const float4*)(s + i * 8 + 4);
        *(uint4*)(d + i * 8) = pk8(a, b);
    }
}

// C = A[M,K]·W[N,K]^T + bias, bf16 in, global_load_lds staging.
// Depth-2 software pipeline: 3 LDS buffer sets, counted s_waitcnt vmcnt(4),
// one raw s_barrier per K-step. Chunk-XOR swizzled LDS via pre-swizzled
// global source + swizzled ds_read (gll dest stays linear).
// mode 0: q -> Q^T [bh][d][s] packed 8B (pre-scaled by SCQ), k -> row-scatter,
// v -> V^T [bh][d][s] packed 8B; mode 1: fp32 store.
__global__ __launch_bounds__(256)
void gemm_bf16(const unsigned short* __restrict__ A,
               const unsigned short* __restrict__ W,
               const float* __restrict__ bias,
               unsigned short* __restrict__ o0,
               unsigned short* __restrict__ o1,
               unsigned short* __restrict__ o2,
               float* __restrict__ of,
               int mode)
{
    __shared__ __align__(16) unsigned short lA[3][128 * 32];
    __shared__ __align__(16) unsigned short lB[3][128 * 32];
    const int tid  = threadIdx.x;
    const int lane = tid & 63, wv = tid >> 6;
    const int quad = lane >> 4, l16 = lane & 15;
    const int wm = (wv & 1) * 64, wn = (wv >> 1) * 64;

    // bijective XCD-aware block swizzle (m204)
    const int nwg = gridDim.x * gridDim.y;
    const int bid = blockIdx.y * gridDim.x + blockIdx.x;
    const int xcd = bid & 7, boff = bid >> 3;
    const int qd = nwg >> 3, rm = nwg & 7;
    const int swz = (xcd < rm ? xcd * (qd + 1) : rm * (qd + 1) + (xcd - rm) * qd) + boff;
    const int m0 = (swz / gridDim.x) * 128, n0 = (swz % gridDim.x) * 128;

    f32x4 acc[4][4] = {};

    const int srow0 = wv * 32 + (lane >> 2);
    const int srow1 = srow0 + 16;
    const int csrc  = ((lane & 3) ^ ((lane >> 3) & 3)) * 8;
    const unsigned short* pa0 = A + (long)(m0 + srow0) * HID + csrc;
    const unsigned short* pa1 = A + (long)(m0 + srow1) * HID + csrc;
    const unsigned short* pb0 = W + (long)(n0 + srow0) * HID + csrc;
    const unsigned short* pb1 = W + (long)(n0 + srow1) * HID + csrc;

    const int cq8 = (quad ^ ((l16 >> 1) & 3)) * 8;

#define STAGE_G(bufi, koff)                                        \
    do {                                                           \
        gll16(pa0 + (koff), &lA[bufi][(wv * 2 + 0) * 512]);        \
        gll16(pa1 + (koff), &lA[bufi][(wv * 2 + 1) * 512]);        \
        gll16(pb0 + (koff), &lB[bufi][(wv * 2 + 0) * 512]);        \
        gll16(pb1 + (koff), &lB[bufi][(wv * 2 + 1) * 512]);        \
    } while (0)

    STAGE_G(0, 0);
    STAGE_G(1, 32);

    int cur = 0;
    for (int k0 = 0; k0 < HID; k0 += 32) {
        if (k0 + 32 < HID) { asm volatile("s_waitcnt vmcnt(4)" ::: "memory"); }
        else               { asm volatile("s_waitcnt vmcnt(0)" ::: "memory"); }
        __builtin_amdgcn_s_barrier();
        asm volatile("" ::: "memory");

        if (k0 + 64 < HID) {
            const int nxt = cur ? cur - 1 : 2;       // (cur+2) mod 3
            STAGE_G(nxt, k0 + 64);
        }

        bf16x8 af[4], bfr[4];
#pragma unroll
        for (int mt = 0; mt < 4; mt++)
            af[mt] = *(const bf16x8*)&lA[cur][(wm + mt * 16 + l16) * 32 + cq8];
#pragma unroll
        for (int nt = 0; nt < 4; nt++)
            bfr[nt] = *(const bf16x8*)&lB[cur][(wn + nt * 16 + l16) * 32 + cq8];
#pragma unroll
        for (int mt = 0; mt < 4; mt++)
#pragma unroll
            for (int nt = 0; nt < 4; nt++)
                acc[mt][nt] = __builtin_amdgcn_mfma_f32_16x16x32_bf16(
                    af[mt], bfr[nt], acc[mt][nt], 0, 0, 0);

        cur = (cur < 2) ? cur + 1 : 0;
    }
#undef STAGE_G

    if (mode == 0) {
#pragma unroll
        for (int nt = 0; nt < 4; nt++) {
            const int n = n0 + wn + nt * 16 + l16;
            const float bv = bias[n];
            const int part = n >> 10, f = n & 1023, h = f >> 6, d = f & 63;
#pragma unroll
            for (int mt = 0; mt < 4; mt++) {
                const int mbase = m0 + wm + mt * 16 + quad * 4;
                const int b = mbase >> 11, s0 = mbase & 2047;
                const int bh = b * NH + h;
                if (part != 1) {
                    // Q^T / V^T: 4 consecutive s per lane -> one packed 8B store.
                    // q additionally gets the softmax scale folded in.
                    const float qsc = (part == 0) ? SCQ : 1.0f;
                    unsigned short* dst = (part == 0) ? o0 : o2;
                    uint2 o;
                    o.x = pk2((acc[mt][nt][0] + bv) * qsc, (acc[mt][nt][1] + bv) * qsc);
                    o.y = pk2((acc[mt][nt][2] + bv) * qsc, (acc[mt][nt][3] + bv) * qsc);
                    *(uint2*)&dst[((long)bh * HD + d) * S_LEN + s0] = o;
                } else {
                    // K stays row-major [bh][s][d] (row-scatter)
#pragma unroll
                    for (int r = 0; r < 4; r++) {
                        union { __hip_bfloat16 h; unsigned short u; } cv;
                        cv.h = __float2bfloat16(acc[mt][nt][r] + bv);
                        o1[((long)bh * S_LEN + s0 + r) * HD + d] = cv.u;
                    }
                }
            }
        }
    } else {
#pragma unroll
        for (int nt = 0; nt < 4; nt++) {
            const int n = n0 + wn + nt * 16 + l16;
            const float bv = bias[n];
#pragma unroll
            for (int mt = 0; mt < 4; mt++) {
                const int mbase = m0 + wm + mt * 16 + quad * 4;
#pragma unroll
                for (int r = 0; r < 4; r++)
                    of[(long)(mbase + r) * HID + n] = acc[mt][nt][r] + bv;
            }
        }
    }
}

// Flash attention, 32x32 swapped-QK form. 256 threads (4 waves), 32 q-rows per
// wave, 64-key tiles. D-layout col = lane&31: a q-row's scores live in the
// LANE PAIR (l, l+32) — row max/sum are per-lane partials pair-combined via
// permlane32_swap (VALU-only, no LDS). P stays in registers: cvt_pk pairs +
// permlane32_swap rebuild the PV B-fragments (T12). kt/vt XOR-granule-swizzled
// (granule ^= row&7). Dbuf LDS + one lgkm-only barrier per tile.
__global__ __launch_bounds__(256)
void attn(const unsigned short* __restrict__ q,     // Q^T [b,h,64,S], pre-scaled
          const unsigned short* __restrict__ k,     // K   [b,h,S,64]
          const unsigned short* __restrict__ vt_g,  // V^T [b,h,64,S]
          const int* __restrict__ mask,
          unsigned short* __restrict__ ctx)         // [b,S,1024] bf16
{
    __shared__ __align__(16) unsigned short kt[2][64 * STK];
    __shared__ __align__(16) unsigned short vt[2][64 * STK];
    __shared__ __align__(16) float mkv[2][64];

    const int tid  = threadIdx.x;
    const int lane = tid & 63, wv = tid >> 6;          // wv 0..3
    const int ar = lane & 31, hi = lane >> 5;
    const int qt = blockIdx.x, h = blockIdx.y, b = blockIdx.z;
    const int bh = b * NH + h;
    const int sq = qt * 128 + wv * 32 + ar;

    // Q fragments (one-time): qf[t][j] = Q[sq][d = 16t + 8hi + j] from Q^T
    union { unsigned short u[8]; bf16x8 v; } qu[4];
    const unsigned short* qg = q + (long)bh * HD * S_LEN + sq;
#pragma unroll
    for (int t = 0; t < 4; t++)
#pragma unroll
        for (int j = 0; j < 8; j++)
            qu[t].u[j] = qg[(long)(16 * t + 8 * hi + j) * S_LEN];

    float mrun = -1e30f, lsum = 0.f;
    f32x16 Of0 = {}, Of1 = {};

    // staging: 256 threads; thread -> row sr (0..63), granules c0 and c0+4.
    // LDS granule is XOR-swizzled by (row&7); reads apply the same XOR.
    const int sr = tid >> 2, c0 = tid & 3;
    const unsigned short* kg = k    + ((long)bh * S_LEN + sr) * HD + c0 * 8;
    const unsigned short* vg = vt_g + ((long)bh * HD + sr) * S_LEN + c0 * 8;
    const int wof0 = sr * STK + ((c0 ^ (sr & 7)) * 8);
    const int wof1 = sr * STK + (((c0 + 4) ^ (sr & 7)) * 8);
    const int swzr = ar & 7;

    // prologue: tile 0 -> buf0; tile 1 -> regs
    uint4 rk0 = *(const uint4*)(kg);
    uint4 rk1 = *(const uint4*)(kg + 32);
    uint4 rv0 = *(const uint4*)(vg);
    uint4 rv1 = *(const uint4*)(vg + 32);
    float rmv = 0.f;
    if (tid < 64) rmv = (mask[b * S_LEN + tid] == 0) ? -1e9f : 0.f;
    *(uint4*)&kt[0][wof0] = rk0;
    *(uint4*)&kt[0][wof1] = rk1;
    *(uint4*)&vt[0][wof0] = rv0;
    *(uint4*)&vt[0][wof1] = rv1;
    if (tid < 64) mkv[0][tid] = rmv;
    rk0 = *(const uint4*)(kg + (long)64 * HD);
    rk1 = *(const uint4*)(kg + (long)64 * HD + 32);
    rv0 = *(const uint4*)(vg + 64);
    rv1 = *(const uint4*)(vg + 64 + 32);
    if (tid < 64) rmv = (mask[b * S_LEN + 64 + tid] == 0) ? -1e9f : 0.f;
    asm volatile("s_waitcnt lgkmcnt(0)" ::: "memory");
    __builtin_amdgcn_s_barrier();
    asm volatile("" ::: "memory");

    for (int k0 = 0; k0 < S_LEN; k0 += 64) {
        const int cur = (k0 >> 6) & 1;
        // write tile t+1 into the other buffer; issue tile t+2 global loads
        if (k0 + 64 < S_LEN) {
            *(uint4*)&kt[cur ^ 1][wof0] = rk0;
            *(uint4*)&kt[cur ^ 1][wof1] = rk1;
            *(uint4*)&vt[cur ^ 1][wof0] = rv0;
            *(uint4*)&vt[cur ^ 1][wof1] = rv1;
            if (tid < 64) mkv[cur ^ 1][tid] = rmv;
            if (k0 + 128 < S_LEN) {
                rk0 = *(const uint4*)(kg + (long)(k0 + 128) * HD);
                rk1 = *(const uint4*)(kg + (long)(k0 + 128) * HD + 32);
                rv0 = *(const uint4*)(vg + (k0 + 128));
                rv1 = *(const uint4*)(vg + (k0 + 128) + 32);
                if (tid < 64) rmv = (mask[b * S_LEN + k0 + 128 + tid] == 0) ? -1e9f : 0.f;
            }
        }

        // QK^T (swapped): S = K·Q^T -> D[key][q], q = lane&31,
        // key = 32G + 8*(r>>2) + 4*hi + (r&3). Mask added post-MFMA.
        float st[2][16];
        __builtin_amdgcn_s_setprio(1);
#pragma unroll
        for (int G = 0; G < 2; G++) {
            f32x16 s = {};
#pragma unroll
            for (int t = 0; t < 4; t++) {
                bf16x8 kf = *(const bf16x8*)
                    &kt[cur][(G * 32 + ar) * STK + (((2 * t + hi) ^ swzr) * 8)];
                s = __builtin_amdgcn_mfma_f32_32x32x16_bf16(kf, qu[t].v, s, 0, 0, 0);
            }
#pragma unroll
            for (int m = 0; m < 4; m++) {
                const float4 mv = *(const float4*)&mkv[cur][G * 32 + m * 8 + hi * 4];
#pragma unroll
                for (int r2 = 0; r2 < 4; r2++)
                    st[G][m * 4 + r2] = s[m * 4 + r2] + (&mv.x)[r2];
            }
        }
        __builtin_amdgcn_s_setprio(0);

        // per-lane max tree, then PAIR-combine (lane l <-> l+32 share a q-row)
        float pmax = st[0][0];
#pragma unroll
        for (int G = 0; G < 2; G++)
#pragma unroll
            for (int r = 0; r < 16; r++) pmax = fmaxf(pmax, st[G][r]);
        pmax = pair_max(pmax);   // row max, pair-consistent

        // defer-max: rescale only when some row's max grew by > 8 (log2).
        // mrun stays pair-consistent inductively (pmax is).
        if (__any(pmax > mrun + 8.f)) {
            const float mn = fmaxf(mrun, pmax);
            const float alpha = exp2_hw(mrun - mn);
            Of0 *= alpha; Of1 *= alpha; lsum *= alpha;
            mrun = mn;
        }

        // P = exp2(st - mrun); per-lane partial row-sum; pack to bf16 pairs
        unsigned wa[2][4], wb[2][4];
        float ls = 0.f;
#pragma unroll
        for (int G = 0; G < 2; G++) {
            float pr[16];
#pragma unroll
            for (int r = 0; r < 16; r++) {
                pr[r] = exp2_hw(st[G][r] - mrun);
                ls += pr[r];
            }
#pragma unroll
            for (int m = 0; m < 4; m++) {
                wa[G][m] = pk2(pr[4 * m + 0], pr[4 * m + 1]);
                wb[G][m] = pk2(pr[4 * m + 2], pr[4 * m + 3]);
            }
        }
        lsum += ls;

        // PV B-fragments in-register (T12): fragment s5 (keys 16s5..16s5+15)
        // for consuming lane hi_c needs row m' = 2*(s5&1)+hi_c:
        //   u[0,1] = hi=0 lane's wa/wb[G][m'];  u[2,3] = hi=1 lane's wa/wb[G][m'].
        // pl32swap(wa[mp], wa[mp+1]) delivers (u[0], u[2]) for BOTH lane halves.
        union { unsigned u[4]; bf16x8 v; } F[4];
#pragma unroll
        for (int s5 = 0; s5 < 4; s5++) {
            const int G = s5 >> 1, mp = (s5 & 1) * 2;
            unsigned f0 = wa[G][mp], f2 = wa[G][mp + 1];
            unsigned f1 = wb[G][mp], f3 = wb[G][mp + 1];
            pl32swap(f0, f2);
            pl32swap(f1, f3);
            F[s5].u[0] = f0; F[s5].u[1] = f1; F[s5].u[2] = f2; F[s5].u[3] = f3;
        }

        // PV: O = V^T · P -> D[d][q]; A-frag = V^T[32g + (lane&31)][key-slice]
        __builtin_amdgcn_s_setprio(1);
#pragma unroll
        for (int s5 = 0; s5 < 4; s5++) {
            bf16x8 vf0 = *(const bf16x8*)
                &vt[cur][(0 * 32 + ar) * STK + (((2 * s5 + hi) ^ swzr) * 8)];
            Of0 = __builtin_amdgcn_mfma_f32_32x32x16_bf16(vf0, F[s5].v, Of0, 0, 0, 0);
            bf16x8 vf1 = *(const bf16x8*)
                &vt[cur][(1 * 32 + ar) * STK + (((2 * s5 + hi) ^ swzr) * 8)];
            Of1 = __builtin_amdgcn_mfma_f32_32x32x16_bf16(vf1, F[s5].v, Of1, 0, 0, 0);
        }
        __builtin_amdgcn_s_setprio(0);

        // one barrier per tile (lgkm-only; global prefetch stays in flight)
        asm volatile("s_waitcnt lgkmcnt(0)" ::: "memory");
        __builtin_amdgcn_s_barrier();
        asm volatile("" ::: "memory");
    }

    // epilogue: pair-sum the row denominator once, then in-lane normalize.
    // d = 32g + 8m + 4hi + (0..3)
    const float inv = 1.f / pair_sum(lsum);
    unsigned short* cb = ctx + ((long)b * S_LEN + sq) * HID + h * HD;
#pragma unroll
    for (int m = 0; m < 4; m++) {
        uint2 o0, o1;
        o0.x = pk2(Of0[4 * m + 0] * inv, Of0[4 * m + 1] * inv);
        o0.y = pk2(Of0[4 * m + 2] * inv, Of0[4 * m + 3] * inv);
        *(uint2*)&cb[m * 8 + hi * 4] = o0;
        o1.x = pk2(Of1[4 * m + 0] * inv, Of1[4 * m + 1] * inv);
        o1.y = pk2(Of1[4 * m + 2] * inv, Of1[4 * m + 3] * inv);
        *(uint2*)&cb[32 + m * 8 + hi * 4] = o1;
    }
}

extern "C" void kernel_launch(void* const* d_in, const int* in_sizes, int n_in,
                              void* d_out, int out_size, void* d_ws, size_t ws_size,
                              hipStream_t stream) {
    float* outp = (float*)d_out;

    const float* x = nullptr; const int* mask = nullptr;
    const float* qkv_w = nullptr; const float* qkv_b = nullptr;
    const float* out_w = nullptr; const float* out_b = nullptr;
    for (int i = 0; i < n_in; i++) {
        switch (in_sizes[i]) {
            case 4194304: x     = (const float*)d_in[i]; break;
            case 4096:    mask  = (const int*)d_in[i];   break;
            case 3145728: qkv_w = (const float*)d_in[i]; break;
            case 3072:    qkv_b = (const float*)d_in[i]; break;
            case 1048576: out_w = (const float*)d_in[i]; break;
            case 1024:    out_b = (const float*)d_in[i]; break;
            default: break;
        }
    }
    if (!x || !mask || !qkv_w || !qkv_b || !out_w || !out_b) {
        fill_constf<<<256, 256, 0, stream>>>(outp, (long)out_size, 1000.0f);
        return;
    }

    const size_t per = (size_t)BATCH * NH * S_LEN * HD;   // 4,194,304
    const size_t nx  = (size_t)BATCH * S_LEN * HID;
    const size_t nqw = (size_t)3 * HID * HID;
    const size_t now = (size_t)HID * HID;
    if (ws_size < 4 * per * sizeof(unsigned short)) {
        fill_constf<<<256, 256, 0, stream>>>(outp, (long)out_size, 2000.0f);
        return;
    }

    // Aliasing discipline (no buffer read+written in the same kernel):
    //   xb  = wsc : dead after gemm1; attn overwrites with ctx
    //   qwb = d_out[0,6.3MB) : dead after gemm1; gemm2 overwrites with output
    //   owb = wsq : written AFTER attn (q dead), read only by gemm2
    unsigned short* wsq = (unsigned short*)d_ws;
    unsigned short* wsk = wsq + per;
    unsigned short* wsv = wsk + per;               // V^T [b,h,64,S]
    unsigned short* wsc = wsv + per;               // phase 1: xb; phase 2: ctx
    unsigned short* xb  = wsc;
    unsigned short* qwb = (unsigned short*)d_out;
    unsigned short* owb = wsq;

    cvt2_bf16<<<1024, 256, 0, stream>>>(x, xb, (long)(nx / 8), qkv_w, qwb, (long)(nqw / 8));
    gemm_bf16<<<dim3(3 * HID / 128, BATCH * S_LEN / 128), 256, 0, stream>>>(
        xb, qwb, qkv_b, wsq, wsk, wsv, nullptr, 0);
    attn<<<dim3(S_LEN / 128, NH, BATCH), 256, 0, stream>>>(wsq, wsk, wsv, mask, wsc);
    cvt_bf16<<<512, 256, 0, stream>>>(out_w, owb, (long)(now / 8));
    gemm_bf16<<<dim3(HID / 128, BATCH * S_LEN / 128), 256, 0, stream>>>(
        wsc, owb, out_b, nullptr, nullptr, nullptr, outp, 1);
}

// Round 6
// 216.871 us; speedup vs baseline: 1.0652x; 1.0652x over previous
//
#include <hip/hip_runtime.h>
#include <hip/hip_bf16.h>

#define S_LEN 2048
#define NH    16
#define HD    64
#define HID   1024
#define BATCH 2
#define STK   72   // kt/vt LDS stride in shorts (144B rows, 16B aligned)
#define SCQ   0.18033688f   // 0.125 * log2(e), folded into q in gemm1 epilogue

typedef __bf16 bf16x8 __attribute__((ext_vector_type(8)));
typedef float  f32x4  __attribute__((ext_vector_type(4)));
typedef float  f32x16 __attribute__((ext_vector_type(16)));
typedef unsigned u32x2 __attribute__((ext_vector_type(2)));

__device__ __forceinline__ unsigned int pk2(float lo, float hi) {
    union { __hip_bfloat162 h; unsigned int u; } c;
    c.h = __float22bfloat162_rn(make_float2(lo, hi));   // v_cvt_pk_bf16_f32
    return c.u;
}
__device__ __forceinline__ uint4 pk8(float4 a, float4 b) {
    uint4 o;
    o.x = pk2(a.x, a.y); o.y = pk2(a.z, a.w);
    o.z = pk2(b.x, b.y); o.w = pk2(b.z, b.w);
    return o;
}
__device__ __forceinline__ float exp2_hw(float x) {
    float r; asm("v_exp_f32 %0, %1" : "=v"(r) : "v"(x)); return r;
}
// v_permlane32_swap_b32 pair exchange (lane l <-> l+32)
__device__ __forceinline__ void pl32swap(unsigned &a, unsigned &b) {
    u32x2 r = __builtin_amdgcn_permlane32_swap(a, b, false, false);
    a = r[0]; b = r[1];
}
// pair-combine helpers: swap(x,x) yields {own, partner} per lane
__device__ __forceinline__ float pair_max(float x) {
    unsigned u = __float_as_uint(x);
    u32x2 r = __builtin_amdgcn_permlane32_swap(u, u, false, false);
    return fmaxf(__uint_as_float(r[0]), __uint_as_float(r[1]));
}
__device__ __forceinline__ float pair_sum(float x) {
    unsigned u = __float_as_uint(x);
    u32x2 r = __builtin_amdgcn_permlane32_swap(u, u, false, false);
    return __uint_as_float(r[0]) + __uint_as_float(r[1]);
}
__device__ __forceinline__ void gll16(const unsigned short* g, unsigned short* l) {
    __builtin_amdgcn_global_load_lds(
        (const __attribute__((address_space(1))) void*)g,
        (__attribute__((address_space(3))) void*)l, 16, 0, 0);
}

__global__ __launch_bounds__(256)
void fill_constf(float* __restrict__ out, long n, float v) {
    long i = (long)blockIdx.x * 256 + threadIdx.x;
    const long stride = (long)gridDim.x * 256;
    for (; i < n; i += stride) out[i] = v;
}

// fp32 -> bf16 bulk convert, 8 elems/iter.
__global__ __launch_bounds__(256)
void cvt_bf16(const float* __restrict__ src, unsigned short* __restrict__ dst, long n8) {
    long t = (long)blockIdx.x * 256 + threadIdx.x;
    const long stride = (long)gridDim.x * 256;
    for (; t < n8; t += stride) {
        const float4 a = *(const float4*)(src + t * 8);
        const float4 b = *(const float4*)(src + t * 8 + 4);
        *(uint4*)(dst + t * 8) = pk8(a, b);
    }
}
// two-tensor variant (x and qkv_w in one launch)
__global__ __launch_bounds__(256)
void cvt2_bf16(const float* __restrict__ s0, unsigned short* __restrict__ d0, long n0,
               const float* __restrict__ s1, unsigned short* __restrict__ d1, long n1) {
    long t = (long)blockIdx.x * 256 + threadIdx.x;
    const long stride = (long)gridDim.x * 256;
    for (; t < n0 + n1; t += stride) {
        const float* s; unsigned short* d; long i;
        if (t < n0) { s = s0; d = d0; i = t; } else { s = s1; d = d1; i = t - n0; }
        const float4 a = *(const float4*)(s + i * 8);
        const float4 b = *(const float4*)(s + i * 8 + 4);
        *(uint4*)(d + i * 8) = pk8(a, b);
    }
}

// C = A[M,K]·W[N,K]^T + bias, bf16 in, global_load_lds staging.
// Depth-2 software pipeline: 3 LDS buffer sets, counted s_waitcnt vmcnt(4),
// one raw s_barrier per K-step. Chunk-XOR swizzled LDS via pre-swizzled
// global source + swizzled ds_read (gll dest stays linear).
// mode 0: q -> Q^T [bh][d][s] packed 8B (pre-scaled by SCQ), k -> row-scatter,
// v -> V^T [bh][d][s] packed 8B; mode 1: fp32 store.
__global__ __launch_bounds__(256)
void gemm_bf16(const unsigned short* __restrict__ A,
               const unsigned short* __restrict__ W,
               const float* __restrict__ bias,
               unsigned short* __restrict__ o0,
               unsigned short* __restrict__ o1,
               unsigned short* __restrict__ o2,
               float* __restrict__ of,
               int mode)
{
    __shared__ __align__(16) unsigned short lA[3][128 * 32];
    __shared__ __align__(16) unsigned short lB[3][128 * 32];
    const int tid  = threadIdx.x;
    const int lane = tid & 63, wv = tid >> 6;
    const int quad = lane >> 4, l16 = lane & 15;
    const int wm = (wv & 1) * 64, wn = (wv >> 1) * 64;

    // bijective XCD-aware block swizzle (m204)
    const int nwg = gridDim.x * gridDim.y;
    const int bid = blockIdx.y * gridDim.x + blockIdx.x;
    const int xcd = bid & 7, boff = bid >> 3;
    const int qd = nwg >> 3, rm = nwg & 7;
    const int swz = (xcd < rm ? xcd * (qd + 1) : rm * (qd + 1) + (xcd - rm) * qd) + boff;
    const int m0 = (swz / gridDim.x) * 128, n0 = (swz % gridDim.x) * 128;

    f32x4 acc[4][4] = {};

    const int srow0 = wv * 32 + (lane >> 2);
    const int srow1 = srow0 + 16;
    const int csrc  = ((lane & 3) ^ ((lane >> 3) & 3)) * 8;
    const unsigned short* pa0 = A + (long)(m0 + srow0) * HID + csrc;
    const unsigned short* pa1 = A + (long)(m0 + srow1) * HID + csrc;
    const unsigned short* pb0 = W + (long)(n0 + srow0) * HID + csrc;
    const unsigned short* pb1 = W + (long)(n0 + srow1) * HID + csrc;

    const int cq8 = (quad ^ ((l16 >> 1) & 3)) * 8;

#define STAGE_G(bufi, koff)                                        \
    do {                                                           \
        gll16(pa0 + (koff), &lA[bufi][(wv * 2 + 0) * 512]);        \
        gll16(pa1 + (koff), &lA[bufi][(wv * 2 + 1) * 512]);        \
        gll16(pb0 + (koff), &lB[bufi][(wv * 2 + 0) * 512]);        \
        gll16(pb1 + (koff), &lB[bufi][(wv * 2 + 1) * 512]);        \
    } while (0)

    STAGE_G(0, 0);
    STAGE_G(1, 32);

    int cur = 0;
    for (int k0 = 0; k0 < HID; k0 += 32) {
        if (k0 + 32 < HID) { asm volatile("s_waitcnt vmcnt(4)" ::: "memory"); }
        else               { asm volatile("s_waitcnt vmcnt(0)" ::: "memory"); }
        __builtin_amdgcn_s_barrier();
        asm volatile("" ::: "memory");

        if (k0 + 64 < HID) {
            const int nxt = cur ? cur - 1 : 2;       // (cur+2) mod 3
            STAGE_G(nxt, k0 + 64);
        }

        bf16x8 af[4], bfr[4];
#pragma unroll
        for (int mt = 0; mt < 4; mt++)
            af[mt] = *(const bf16x8*)&lA[cur][(wm + mt * 16 + l16) * 32 + cq8];
#pragma unroll
        for (int nt = 0; nt < 4; nt++)
            bfr[nt] = *(const bf16x8*)&lB[cur][(wn + nt * 16 + l16) * 32 + cq8];
#pragma unroll
        for (int mt = 0; mt < 4; mt++)
#pragma unroll
            for (int nt = 0; nt < 4; nt++)
                acc[mt][nt] = __builtin_amdgcn_mfma_f32_16x16x32_bf16(
                    af[mt], bfr[nt], acc[mt][nt], 0, 0, 0);

        cur = (cur < 2) ? cur + 1 : 0;
    }
#undef STAGE_G

    if (mode == 0) {
#pragma unroll
        for (int nt = 0; nt < 4; nt++) {
            const int n = n0 + wn + nt * 16 + l16;
            const float bv = bias[n];
            const int part = n >> 10, f = n & 1023, h = f >> 6, d = f & 63;
#pragma unroll
            for (int mt = 0; mt < 4; mt++) {
                const int mbase = m0 + wm + mt * 16 + quad * 4;
                const int b = mbase >> 11, s0 = mbase & 2047;
                const int bh = b * NH + h;
                if (part != 1) {
                    // Q^T / V^T: 4 consecutive s per lane -> one packed 8B store.
                    // q additionally gets the softmax scale folded in.
                    const float qsc = (part == 0) ? SCQ : 1.0f;
                    unsigned short* dst = (part == 0) ? o0 : o2;
                    uint2 o;
                    o.x = pk2((acc[mt][nt][0] + bv) * qsc, (acc[mt][nt][1] + bv) * qsc);
                    o.y = pk2((acc[mt][nt][2] + bv) * qsc, (acc[mt][nt][3] + bv) * qsc);
                    *(uint2*)&dst[((long)bh * HD + d) * S_LEN + s0] = o;
                } else {
                    // K stays row-major [bh][s][d] (row-scatter)
#pragma unroll
                    for (int r = 0; r < 4; r++) {
                        union { __hip_bfloat16 h; unsigned short u; } cv;
                        cv.h = __float2bfloat16(acc[mt][nt][r] + bv);
                        o1[((long)bh * S_LEN + s0 + r) * HD + d] = cv.u;
                    }
                }
            }
        }
    } else {
#pragma unroll
        for (int nt = 0; nt < 4; nt++) {
            const int n = n0 + wn + nt * 16 + l16;
            const float bv = bias[n];
#pragma unroll
            for (int mt = 0; mt < 4; mt++) {
                const int mbase = m0 + wm + mt * 16 + quad * 4;
#pragma unroll
                for (int r = 0; r < 4; r++)
                    of[(long)(mbase + r) * HID + n] = acc[mt][nt][r] + bv;
            }
        }
    }
}

// Flash attention, 32x32 swapped-QK form, KEY-SPLIT wave pairs.
// 512 threads = 8 waves = 4 q-chunks x 2 key-parities. Wave (c,p) handles
// q-rows [qt*128 + 32c, +32) over key-group 32p..32p+31 of every 64-key tile:
// 4 QK + 4 PV MFMA and 16 exp2 per tile per wave. Each parity keeps its own
// (O, m, l); a one-time LDS merge (overlaying the dead kt/vt staging)
// flash-combines the pair. No LDS swizzle: STK=72's natural 4-bank/row
// rotation already puts every ds_read/ds_write pattern at the wave64 floor.
// Per-q-row state is split across the lane pair (l, l+32); permlane32_swap
// pair-combines max/sum and rebuilds PV B-fragments in-register (T12).
__global__ __launch_bounds__(512)
void attn(const unsigned short* __restrict__ q,     // Q^T [b,h,64,S], pre-scaled
          const unsigned short* __restrict__ k,     // K   [b,h,S,64]
          const unsigned short* __restrict__ vt_g,  // V^T [b,h,64,S]
          const int* __restrict__ mask,
          unsigned short* __restrict__ ctx)         // [b,S,1024] bf16
{
    __shared__ __align__(16) unsigned short kt[2][64 * STK];
    __shared__ __align__(16) unsigned short vt[2][64 * STK];
    __shared__ __align__(16) float mkv[2][64];

    const int tid  = threadIdx.x;
    const int lane = tid & 63, wv = tid >> 6;          // wv 0..7
    const int ar = lane & 31, hi = lane >> 5;
    const int chunk = wv >> 1, p = wv & 1;             // q-chunk, key parity
    const int qt = blockIdx.x, h = blockIdx.y, b = blockIdx.z;
    const int bh = b * NH + h;
    const int sq = qt * 128 + chunk * 32 + ar;

    // Q fragments (one-time): qu[t][j] = Q[sq][d = 16t + 8hi + j] from Q^T
    union { unsigned short u[8]; bf16x8 v; } qu[4];
    const unsigned short* qg = q + (long)bh * HD * S_LEN + sq;
#pragma unroll
    for (int t = 0; t < 4; t++)
#pragma unroll
        for (int j = 0; j < 8; j++)
            qu[t].u[j] = qg[(long)(16 * t + 8 * hi + j) * S_LEN];

    float mrun = -1e30f, lsum = 0.f;
    f32x16 Of0 = {}, Of1 = {};

    // staging: 512 threads cover 64 rows x 8 granules, ONE uint4 per matrix
    const int sr = tid >> 3, c0 = tid & 7;
    const unsigned short* kg = k    + ((long)bh * S_LEN + sr) * HD + c0 * 8;
    const unsigned short* vg = vt_g + ((long)bh * HD + sr) * S_LEN + c0 * 8;
    const int wof = sr * STK + c0 * 8;

    // prologue: tile 0 -> buf0; tile 1 -> regs
    uint4 rk = *(const uint4*)(kg);
    uint4 rv = *(const uint4*)(vg);
    float rmv = 0.f;
    if (tid < 64) rmv = (mask[b * S_LEN + tid] == 0) ? -1e9f : 0.f;
    *(uint4*)&kt[0][wof] = rk;
    *(uint4*)&vt[0][wof] = rv;
    if (tid < 64) mkv[0][tid] = rmv;
    rk = *(const uint4*)(kg + (long)64 * HD);
    rv = *(const uint4*)(vg + 64);
    if (tid < 64) rmv = (mask[b * S_LEN + 64 + tid] == 0) ? -1e9f : 0.f;
    asm volatile("s_waitcnt lgkmcnt(0)" ::: "memory");
    __builtin_amdgcn_s_barrier();
    asm volatile("" ::: "memory");

    for (int k0 = 0; k0 < S_LEN; k0 += 64) {
        const int cur = (k0 >> 6) & 1;
        // write tile t+1 into the other buffer; issue tile t+2 global loads
        if (k0 + 64 < S_LEN) {
            *(uint4*)&kt[cur ^ 1][wof] = rk;
            *(uint4*)&vt[cur ^ 1][wof] = rv;
            if (tid < 64) mkv[cur ^ 1][tid] = rmv;
            if (k0 + 128 < S_LEN) {
                rk = *(const uint4*)(kg + (long)(k0 + 128) * HD);
                rv = *(const uint4*)(vg + (k0 + 128));
                if (tid < 64) rmv = (mask[b * S_LEN + k0 + 128 + tid] == 0) ? -1e9f : 0.f;
            }
        }

        // QK^T (swapped) over MY key group: S = K·Q^T -> D[key][q], q=lane&31,
        // key = 32p + 8*(r>>2) + 4*hi + (r&3). Mask added post-MFMA.
        float st[16];
        __builtin_amdgcn_s_setprio(1);
        {
            f32x16 s = {};
#pragma unroll
            for (int t = 0; t < 4; t++) {
                bf16x8 kf = *(const bf16x8*)
                    &kt[cur][(p * 32 + ar) * STK + (2 * t + hi) * 8];
                s = __builtin_amdgcn_mfma_f32_32x32x16_bf16(kf, qu[t].v, s, 0, 0, 0);
            }
            __builtin_amdgcn_s_setprio(0);
#pragma unroll
            for (int m = 0; m < 4; m++) {
                const float4 mv = *(const float4*)&mkv[cur][p * 32 + m * 8 + hi * 4];
#pragma unroll
                for (int r2 = 0; r2 < 4; r2++)
                    st[m * 4 + r2] = s[m * 4 + r2] + (&mv.x)[r2];
            }
        }

        // per-lane max tree, then PAIR-combine (lane l <-> l+32 share a q-row)
        float pmax = fmaxf(fmaxf(fmaxf(st[0], st[1]), fmaxf(st[2], st[3])),
                     fmaxf(fmaxf(st[4], st[5]), fmaxf(st[6], st[7])));
        pmax = fmaxf(pmax,
                fmaxf(fmaxf(fmaxf(st[8], st[9]), fmaxf(st[10], st[11])),
                      fmaxf(fmaxf(st[12], st[13]), fmaxf(st[14], st[15]))));
        pmax = pair_max(pmax);   // row max within my key group, pair-consistent

        // defer-max: rescale only when some row's max grew by > 8 (log2)
        if (__any(pmax > mrun + 8.f)) {
            const float mn = fmaxf(mrun, pmax);
            const float alpha = exp2_hw(mrun - mn);
            Of0 *= alpha; Of1 *= alpha; lsum *= alpha;
            mrun = mn;
        }

        // P = exp2(st - mrun); per-lane partial row-sum; pack to bf16 pairs
        float pr[16];
        float ls = 0.f;
#pragma unroll
        for (int r = 0; r < 16; r++) {
            pr[r] = exp2_hw(st[r] - mrun);
            ls += pr[r];
        }
        lsum += ls;
        unsigned wa[4], wb[4];
#pragma unroll
        for (int m = 0; m < 4; m++) {
            wa[m] = pk2(pr[4 * m + 0], pr[4 * m + 1]);
            wb[m] = pk2(pr[4 * m + 2], pr[4 * m + 3]);
        }

        // PV B-fragments in-register (T12): local fragment s5l (keys
        // 16*(2p+s5l)..+15) uses rows m' = 2*s5l + hi_c:
        // pl32swap(wa[mp], wa[mp+1]) delivers (u[0], u[2]) for BOTH halves.
        union { unsigned u[4]; bf16x8 v; } F[2];
#pragma unroll
        for (int s5 = 0; s5 < 2; s5++) {
            const int mp = s5 * 2;
            unsigned f0 = wa[mp], f2 = wa[mp + 1];
            unsigned f1 = wb[mp], f3 = wb[mp + 1];
            pl32swap(f0, f2);
            pl32swap(f1, f3);
            F[s5].u[0] = f0; F[s5].u[1] = f1; F[s5].u[2] = f2; F[s5].u[3] = f3;
        }

        // PV: O += V^T · P -> D[d][q]; A-frag = V^T[32g + ar][key-slice 2p+s5]
        __builtin_amdgcn_s_setprio(1);
#pragma unroll
        for (int s5 = 0; s5 < 2; s5++) {
            const int gr = (2 * (2 * p + s5) + hi) * 8;
            bf16x8 vf0 = *(const bf16x8*)&vt[cur][(0 * 32 + ar) * STK + gr];
            Of0 = __builtin_amdgcn_mfma_f32_32x32x16_bf16(vf0, F[s5].v, Of0, 0, 0, 0);
            bf16x8 vf1 = *(const bf16x8*)&vt[cur][(1 * 32 + ar) * STK + gr];
            Of1 = __builtin_amdgcn_mfma_f32_32x32x16_bf16(vf1, F[s5].v, Of1, 0, 0, 0);
        }
        __builtin_amdgcn_s_setprio(0);

        // one barrier per tile (lgkm-only; global prefetch stays in flight)
        asm volatile("s_waitcnt lgkmcnt(0)" ::: "memory");
        __builtin_amdgcn_s_barrier();
        asm volatile("" ::: "memory");
    }

    // ---- parity merge: flash-combine (O,m,l) of p=0 and p=1 waves ----
    // Overlay the dead staging LDS: kt <- Of0 partials (4096 f32),
    // vt <- Of1 partials (4096 f32) + [m,l] (512 f32). XOR on the m-index
    // keeps writes/reads at the bank floor.
    const float lp = pair_sum(lsum);           // row sum within my key group
    float* mo0 = (float*)&kt[0][0];
    float* mo1 = (float*)&vt[0][0];
    float* mml = (float*)&vt[0][0] + 4096;
    const int mbase = (chunk * 64 + lane) * 16;
    const int mx4 = (lane >> 1) & 3;
    if (p == 1) {
#pragma unroll
        for (int m = 0; m < 4; m++) {
            const int off = mbase + ((m ^ mx4) << 2);
            *(float4*)&mo0[off] = make_float4(Of0[4*m+0], Of0[4*m+1], Of0[4*m+2], Of0[4*m+3]);
            *(float4*)&mo1[off] = make_float4(Of1[4*m+0], Of1[4*m+1], Of1[4*m+2], Of1[4*m+3]);
        }
        mml[(chunk * 64 + lane) * 2 + 0] = mrun;
        mml[(chunk * 64 + lane) * 2 + 1] = lp;
    }
    __syncthreads();
    if (p == 0) {
        const float m1 = mml[(chunk * 64 + lane) * 2 + 0];
        const float l1 = mml[(chunk * 64 + lane) * 2 + 1];
        const float mm = fmaxf(mrun, m1);
        const float a0 = exp2_hw(mrun - mm);
        const float a1 = exp2_hw(m1 - mm);
        const float inv = 1.f / (lp * a0 + l1 * a1);
        // d = 32g + 8m + 4hi + (0..3)
        unsigned short* cb = ctx + ((long)b * S_LEN + sq) * HID + h * HD;
#pragma unroll
        for (int m = 0; m < 4; m++) {
            const int off = mbase + ((m ^ mx4) << 2);
            const float4 p0 = *(const float4*)&mo0[off];
            const float4 p1 = *(const float4*)&mo1[off];
            uint2 o0, o1;
            o0.x = pk2((Of0[4*m+0] * a0 + p0.x * a1) * inv,
                       (Of0[4*m+1] * a0 + p0.y * a1) * inv);
            o0.y = pk2((Of0[4*m+2] * a0 + p0.z * a1) * inv,
                       (Of0[4*m+3] * a0 + p0.w * a1) * inv);
            *(uint2*)&cb[m * 8 + hi * 4] = o0;
            o1.x = pk2((Of1[4*m+0] * a0 + p1.x * a1) * inv,
                       (Of1[4*m+1] * a0 + p1.y * a1) * inv);
            o1.y = pk2((Of1[4*m+2] * a0 + p1.z * a1) * inv,
                       (Of1[4*m+3] * a0 + p1.w * a1) * inv);
            *(uint2*)&cb[32 + m * 8 + hi * 4] = o1;
        }
    }
}

extern "C" void kernel_launch(void* const* d_in, const int* in_sizes, int n_in,
                              void* d_out, int out_size, void* d_ws, size_t ws_size,
                              hipStream_t stream) {
    float* outp = (float*)d_out;

    const float* x = nullptr; const int* mask = nullptr;
    const float* qkv_w = nullptr; const float* qkv_b = nullptr;
    const float* out_w = nullptr; const float* out_b = nullptr;
    for (int i = 0; i < n_in; i++) {
        switch (in_sizes[i]) {
            case 4194304: x     = (const float*)d_in[i]; break;
            case 4096:    mask  = (const int*)d_in[i];   break;
            case 3145728: qkv_w = (const float*)d_in[i]; break;
            case 3072:    qkv_b = (const float*)d_in[i]; break;
            case 1048576: out_w = (const float*)d_in[i]; break;
            case 1024:    out_b = (const float*)d_in[i]; break;
            default: break;
        }
    }
    if (!x || !mask || !qkv_w || !qkv_b || !out_w || !out_b) {
        fill_constf<<<256, 256, 0, stream>>>(outp, (long)out_size, 1000.0f);
        return;
    }

    const size_t per = (size_t)BATCH * NH * S_LEN * HD;   // 4,194,304
    const size_t nx  = (size_t)BATCH * S_LEN * HID;
    const size_t nqw = (size_t)3 * HID * HID;
    const size_t now = (size_t)HID * HID;
    if (ws_size < 4 * per * sizeof(unsigned short)) {
        fill_constf<<<256, 256, 0, stream>>>(outp, (long)out_size, 2000.0f);
        return;
    }

    // Aliasing discipline (no buffer read+written in the same kernel):
    //   xb  = wsc : dead after gemm1; attn overwrites with ctx
    //   qwb = d_out[0,6.3MB) : dead after gemm1; gemm2 overwrites with output
    //   owb = wsq : written AFTER attn (q dead), read only by gemm2
    unsigned short* wsq = (unsigned short*)d_ws;
    unsigned short* wsk = wsq + per;
    unsigned short* wsv = wsk + per;               // V^T [b,h,64,S]
    unsigned short* wsc = wsv + per;               // phase 1: xb; phase 2: ctx
    unsigned short* xb  = wsc;
    unsigned short* qwb = (unsigned short*)d_out;
    unsigned short* owb = wsq;

    cvt2_bf16<<<1024, 256, 0, stream>>>(x, xb, (long)(nx / 8), qkv_w, qwb, (long)(nqw / 8));
    gemm_bf16<<<dim3(3 * HID / 128, BATCH * S_LEN / 128), 256, 0, stream>>>(
        xb, qwb, qkv_b, wsq, wsk, wsv, nullptr, 0);
    attn<<<dim3(S_LEN / 128, NH, BATCH), 512, 0, stream>>>(wsq, wsk, wsv, mask, wsc);
    cvt_bf16<<<512, 256, 0, stream>>>(out_w, owb, (long)(now / 8));
    gemm_bf16<<<dim3(HID / 128, BATCH * S_LEN / 128), 256, 0, stream>>>(
        wsc, owb, out_b, nullptr, nullptr, nullptr, outp, 1);
}

// Round 7
// 211.979 us; speedup vs baseline: 1.0898x; 1.0231x over previous
//
#include <hip/hip_runtime.h>
#include <hip/hip_bf16.h>

#define S_LEN 2048
#define NH    16
#define HD    64
#define HID   1024
#define BATCH 2
#define STK   72   // kt/vt LDS stride in shorts (144B rows, 16B aligned)
#define SCQ   0.18033688f   // 0.125 * log2(e), folded into q in gemm1 epilogue

typedef __bf16 bf16x8 __attribute__((ext_vector_type(8)));
typedef float  f32x4  __attribute__((ext_vector_type(4)));
typedef float  f32x16 __attribute__((ext_vector_type(16)));
typedef unsigned u32x2 __attribute__((ext_vector_type(2)));

__device__ __forceinline__ unsigned int pk2(float lo, float hi) {
    union { __hip_bfloat162 h; unsigned int u; } c;
    c.h = __float22bfloat162_rn(make_float2(lo, hi));   // v_cvt_pk_bf16_f32
    return c.u;
}
__device__ __forceinline__ uint4 pk8(float4 a, float4 b) {
    uint4 o;
    o.x = pk2(a.x, a.y); o.y = pk2(a.z, a.w);
    o.z = pk2(b.x, b.y); o.w = pk2(b.z, b.w);
    return o;
}
__device__ __forceinline__ float exp2_hw(float x) {
    float r; asm("v_exp_f32 %0, %1" : "=v"(r) : "v"(x)); return r;
}
// v_permlane32_swap_b32 pair exchange (lane l <-> l+32)
__device__ __forceinline__ void pl32swap(unsigned &a, unsigned &b) {
    u32x2 r = __builtin_amdgcn_permlane32_swap(a, b, false, false);
    a = r[0]; b = r[1];
}
// pair-combine helpers: swap(x,x) yields {own, partner} per lane
__device__ __forceinline__ float pair_max(float x) {
    unsigned u = __float_as_uint(x);
    u32x2 r = __builtin_amdgcn_permlane32_swap(u, u, false, false);
    return fmaxf(__uint_as_float(r[0]), __uint_as_float(r[1]));
}
__device__ __forceinline__ float pair_sum(float x) {
    unsigned u = __float_as_uint(x);
    u32x2 r = __builtin_amdgcn_permlane32_swap(u, u, false, false);
    return __uint_as_float(r[0]) + __uint_as_float(r[1]);
}
__device__ __forceinline__ void gll16(const unsigned short* g, unsigned short* l) {
    __builtin_amdgcn_global_load_lds(
        (const __attribute__((address_space(1))) void*)g,
        (__attribute__((address_space(3))) void*)l, 16, 0, 0);
}

__global__ __launch_bounds__(256)
void fill_constf(float* __restrict__ out, long n, float v) {
    long i = (long)blockIdx.x * 256 + threadIdx.x;
    const long stride = (long)gridDim.x * 256;
    for (; i < n; i += stride) out[i] = v;
}

// fp32 -> bf16 bulk convert, 8 elems/iter.
__global__ __launch_bounds__(256)
void cvt_bf16(const float* __restrict__ src, unsigned short* __restrict__ dst, long n8) {
    long t = (long)blockIdx.x * 256 + threadIdx.x;
    const long stride = (long)gridDim.x * 256;
    for (; t < n8; t += stride) {
        const float4 a = *(const float4*)(src + t * 8);
        const float4 b = *(const float4*)(src + t * 8 + 4);
        *(uint4*)(dst + t * 8) = pk8(a, b);
    }
}
// two-tensor variant (x and qkv_w in one launch)
__global__ __launch_bounds__(256)
void cvt2_bf16(const float* __restrict__ s0, unsigned short* __restrict__ d0, long n0,
               const float* __restrict__ s1, unsigned short* __restrict__ d1, long n1) {
    long t = (long)blockIdx.x * 256 + threadIdx.x;
    const long stride = (long)gridDim.x * 256;
    for (; t < n0 + n1; t += stride) {
        const float* s; unsigned short* d; long i;
        if (t < n0) { s = s0; d = d0; i = t; } else { s = s1; d = d1; i = t - n0; }
        const float4 a = *(const float4*)(s + i * 8);
        const float4 b = *(const float4*)(s + i * 8 + 4);
        *(uint4*)(d + i * 8) = pk8(a, b);
    }
}

// C = A[M,K]·W[N,K]^T + bias, bf16 in, global_load_lds staging.
// Depth-2 software pipeline: 3 LDS buffer sets, counted s_waitcnt vmcnt(4),
// one raw s_barrier per K-step. Chunk-XOR swizzled LDS via pre-swizzled
// global source + swizzled ds_read (gll dest stays linear).
// mode 0: q -> Q^T [bh][d][s] packed 8B (pre-scaled by SCQ), k -> row-scatter,
// v -> V^T [bh][d][s] packed 8B; mode 1: fp32 store.
__global__ __launch_bounds__(256)
void gemm_bf16(const unsigned short* __restrict__ A,
               const unsigned short* __restrict__ W,
               const float* __restrict__ bias,
               unsigned short* __restrict__ o0,
               unsigned short* __restrict__ o1,
               unsigned short* __restrict__ o2,
               float* __restrict__ of,
               int mode)
{
    __shared__ __align__(16) unsigned short lA[3][128 * 32];
    __shared__ __align__(16) unsigned short lB[3][128 * 32];
    const int tid  = threadIdx.x;
    const int lane = tid & 63, wv = tid >> 6;
    const int quad = lane >> 4, l16 = lane & 15;
    const int wm = (wv & 1) * 64, wn = (wv >> 1) * 64;

    // bijective XCD-aware block swizzle (m204)
    const int nwg = gridDim.x * gridDim.y;
    const int bid = blockIdx.y * gridDim.x + blockIdx.x;
    const int xcd = bid & 7, boff = bid >> 3;
    const int qd = nwg >> 3, rm = nwg & 7;
    const int swz = (xcd < rm ? xcd * (qd + 1) : rm * (qd + 1) + (xcd - rm) * qd) + boff;
    const int m0 = (swz / gridDim.x) * 128, n0 = (swz % gridDim.x) * 128;

    f32x4 acc[4][4] = {};

    const int srow0 = wv * 32 + (lane >> 2);
    const int srow1 = srow0 + 16;
    const int csrc  = ((lane & 3) ^ ((lane >> 3) & 3)) * 8;
    const unsigned short* pa0 = A + (long)(m0 + srow0) * HID + csrc;
    const unsigned short* pa1 = A + (long)(m0 + srow1) * HID + csrc;
    const unsigned short* pb0 = W + (long)(n0 + srow0) * HID + csrc;
    const unsigned short* pb1 = W + (long)(n0 + srow1) * HID + csrc;

    const int cq8 = (quad ^ ((l16 >> 1) & 3)) * 8;

#define STAGE_G(bufi, koff)                                        \
    do {                                                           \
        gll16(pa0 + (koff), &lA[bufi][(wv * 2 + 0) * 512]);        \
        gll16(pa1 + (koff), &lA[bufi][(wv * 2 + 1) * 512]);        \
        gll16(pb0 + (koff), &lB[bufi][(wv * 2 + 0) * 512]);        \
        gll16(pb1 + (koff), &lB[bufi][(wv * 2 + 1) * 512]);        \
    } while (0)

    STAGE_G(0, 0);
    STAGE_G(1, 32);

    int cur = 0;
    for (int k0 = 0; k0 < HID; k0 += 32) {
        if (k0 + 32 < HID) { asm volatile("s_waitcnt vmcnt(4)" ::: "memory"); }
        else               { asm volatile("s_waitcnt vmcnt(0)" ::: "memory"); }
        __builtin_amdgcn_s_barrier();
        asm volatile("" ::: "memory");

        if (k0 + 64 < HID) {
            const int nxt = cur ? cur - 1 : 2;       // (cur+2) mod 3
            STAGE_G(nxt, k0 + 64);
        }

        bf16x8 af[4], bfr[4];
#pragma unroll
        for (int mt = 0; mt < 4; mt++)
            af[mt] = *(const bf16x8*)&lA[cur][(wm + mt * 16 + l16) * 32 + cq8];
#pragma unroll
        for (int nt = 0; nt < 4; nt++)
            bfr[nt] = *(const bf16x8*)&lB[cur][(wn + nt * 16 + l16) * 32 + cq8];
#pragma unroll
        for (int mt = 0; mt < 4; mt++)
#pragma unroll
            for (int nt = 0; nt < 4; nt++)
                acc[mt][nt] = __builtin_amdgcn_mfma_f32_16x16x32_bf16(
                    af[mt], bfr[nt], acc[mt][nt], 0, 0, 0);

        cur = (cur < 2) ? cur + 1 : 0;
    }
#undef STAGE_G

    if (mode == 0) {
#pragma unroll
        for (int nt = 0; nt < 4; nt++) {
            const int n = n0 + wn + nt * 16 + l16;
            const float bv = bias[n];
            const int part = n >> 10, f = n & 1023, h = f >> 6, d = f & 63;
#pragma unroll
            for (int mt = 0; mt < 4; mt++) {
                const int mbase = m0 + wm + mt * 16 + quad * 4;
                const int b = mbase >> 11, s0 = mbase & 2047;
                const int bh = b * NH + h;
                if (part != 1) {
                    // Q^T / V^T: 4 consecutive s per lane -> one packed 8B store.
                    // q additionally gets the softmax scale folded in.
                    const float qsc = (part == 0) ? SCQ : 1.0f;
                    unsigned short* dst = (part == 0) ? o0 : o2;
                    uint2 o;
                    o.x = pk2((acc[mt][nt][0] + bv) * qsc, (acc[mt][nt][1] + bv) * qsc);
                    o.y = pk2((acc[mt][nt][2] + bv) * qsc, (acc[mt][nt][3] + bv) * qsc);
                    *(uint2*)&dst[((long)bh * HD + d) * S_LEN + s0] = o;
                } else {
                    // K stays row-major [bh][s][d] (row-scatter)
#pragma unroll
                    for (int r = 0; r < 4; r++) {
                        union { __hip_bfloat16 h; unsigned short u; } cv;
                        cv.h = __float2bfloat16(acc[mt][nt][r] + bv);
                        o1[((long)bh * S_LEN + s0 + r) * HD + d] = cv.u;
                    }
                }
            }
        }
    } else {
#pragma unroll
        for (int nt = 0; nt < 4; nt++) {
            const int n = n0 + wn + nt * 16 + l16;
            const float bv = bias[n];
#pragma unroll
            for (int mt = 0; mt < 4; mt++) {
                const int mbase = m0 + wm + mt * 16 + quad * 4;
#pragma unroll
                for (int r = 0; r < 4; r++)
                    of[(long)(mbase + r) * HID + n] = acc[mt][nt][r] + bv;
            }
        }
    }
}

// Output projection GEMM: C = A[4096,1024]·W[1024,1024]^T + bias, fp32 out.
// BN=64 tile -> grid 16x32 = 512 blocks = 2 blocks/CU = 2 waves/SIMD (the
// 128x128 version ran 256 blocks = 1 wave/SIMD, fully latency-exposed).
// Same depth-2 pipeline; 3 loads/tile/wave -> counted vmcnt(3).
__global__ __launch_bounds__(256)
void gemm_out64(const unsigned short* __restrict__ A,
                const unsigned short* __restrict__ W,
                const float* __restrict__ bias,
                float* __restrict__ of)
{
    __shared__ __align__(16) unsigned short lA[3][128 * 32];
    __shared__ __align__(16) unsigned short lB[3][64 * 32];
    const int tid  = threadIdx.x;
    const int lane = tid & 63, wv = tid >> 6;
    const int quad = lane >> 4, l16 = lane & 15;
    const int wm = (wv & 1) * 64, wn = (wv >> 1) * 32;   // wave tile 64M x 32N

    // bijective XCD-aware block swizzle (m204); nwg = 512 (% 8 == 0)
    const int nwg = gridDim.x * gridDim.y;
    const int bid = blockIdx.y * gridDim.x + blockIdx.x;
    const int xcd = bid & 7, boff = bid >> 3;
    const int qd = nwg >> 3, rm = nwg & 7;
    const int swz = (xcd < rm ? xcd * (qd + 1) : rm * (qd + 1) + (xcd - rm) * qd) + boff;
    const int m0 = (swz / gridDim.x) * 128, n0 = (swz % gridDim.x) * 64;

    f32x4 acc[4][2] = {};

    const int arow0 = wv * 32 + (lane >> 2);
    const int arow1 = arow0 + 16;
    const int brow  = wv * 16 + (lane >> 2);
    const int csrc  = ((lane & 3) ^ ((lane >> 3) & 3)) * 8;
    const unsigned short* pa0 = A + (long)(m0 + arow0) * HID + csrc;
    const unsigned short* pa1 = A + (long)(m0 + arow1) * HID + csrc;
    const unsigned short* pb  = W + (long)(n0 + brow ) * HID + csrc;

    const int cq8 = (quad ^ ((l16 >> 1) & 3)) * 8;

#define STAGE_O(bufi, koff)                                        \
    do {                                                           \
        gll16(pa0 + (koff), &lA[bufi][(wv * 2 + 0) * 512]);        \
        gll16(pa1 + (koff), &lA[bufi][(wv * 2 + 1) * 512]);        \
        gll16(pb  + (koff), &lB[bufi][wv * 512]);                  \
    } while (0)

    STAGE_O(0, 0);
    STAGE_O(1, 32);

    int cur = 0;
    for (int k0 = 0; k0 < HID; k0 += 32) {
        if (k0 + 32 < HID) { asm volatile("s_waitcnt vmcnt(3)" ::: "memory"); }
        else               { asm volatile("s_waitcnt vmcnt(0)" ::: "memory"); }
        __builtin_amdgcn_s_barrier();
        asm volatile("" ::: "memory");

        if (k0 + 64 < HID) {
            const int nxt = cur ? cur - 1 : 2;       // (cur+2) mod 3
            STAGE_O(nxt, k0 + 64);
        }

        bf16x8 af[4], bfr[2];
#pragma unroll
        for (int mt = 0; mt < 4; mt++)
            af[mt] = *(const bf16x8*)&lA[cur][(wm + mt * 16 + l16) * 32 + cq8];
#pragma unroll
        for (int nt = 0; nt < 2; nt++)
            bfr[nt] = *(const bf16x8*)&lB[cur][(wn + nt * 16 + l16) * 32 + cq8];
#pragma unroll
        for (int mt = 0; mt < 4; mt++)
#pragma unroll
            for (int nt = 0; nt < 2; nt++)
                acc[mt][nt] = __builtin_amdgcn_mfma_f32_16x16x32_bf16(
                    af[mt], bfr[nt], acc[mt][nt], 0, 0, 0);

        cur = (cur < 2) ? cur + 1 : 0;
    }
#undef STAGE_O

#pragma unroll
    for (int nt = 0; nt < 2; nt++) {
        const int n = n0 + wn + nt * 16 + l16;
        const float bv = bias[n];
#pragma unroll
        for (int mt = 0; mt < 4; mt++) {
            const int mbase = m0 + wm + mt * 16 + quad * 4;
#pragma unroll
            for (int r = 0; r < 4; r++)
                of[(long)(mbase + r) * HID + n] = acc[mt][nt][r] + bv;
        }
    }
}

// Flash attention, 32x32 swapped-QK form, KEY-SPLIT wave pairs.
// 512 threads = 8 waves = 4 q-chunks x 2 key-parities. Wave (c,p) handles
// q-rows [qt*128 + 32c, +32) over key-group 32p..32p+31 of every 64-key tile.
// Mask folded into the MFMA C-init (no post-add). Each parity keeps its own
// (O, m, l); one-time LDS merge flash-combines the pair. Per-q-row state is
// split across the lane pair (l, l+32); permlane32_swap pair-combines max/sum
// and rebuilds PV B-fragments in-register (T12).
__global__ __launch_bounds__(512)
void attn(const unsigned short* __restrict__ q,     // Q^T [b,h,64,S], pre-scaled
          const unsigned short* __restrict__ k,     // K   [b,h,S,64]
          const unsigned short* __restrict__ vt_g,  // V^T [b,h,64,S]
          const int* __restrict__ mask,
          unsigned short* __restrict__ ctx)         // [b,S,1024] bf16
{
    __shared__ __align__(16) unsigned short kt[2][64 * STK];
    __shared__ __align__(16) unsigned short vt[2][64 * STK];
    __shared__ __align__(16) float mkv[2][64];

    const int tid  = threadIdx.x;
    const int lane = tid & 63, wv = tid >> 6;          // wv 0..7
    const int ar = lane & 31, hi = lane >> 5;
    const int chunk = wv >> 1, p = wv & 1;             // q-chunk, key parity
    const int qt = blockIdx.x, h = blockIdx.y, b = blockIdx.z;
    const int bh = b * NH + h;
    const int sq = qt * 128 + chunk * 32 + ar;

    // Q fragments (one-time): qu[t][j] = Q[sq][d = 16t + 8hi + j] from Q^T
    union { unsigned short u[8]; bf16x8 v; } qu[4];
    const unsigned short* qg = q + (long)bh * HD * S_LEN + sq;
#pragma unroll
    for (int t = 0; t < 4; t++)
#pragma unroll
        for (int j = 0; j < 8; j++)
            qu[t].u[j] = qg[(long)(16 * t + 8 * hi + j) * S_LEN];

    float mrun = -1e30f, lsum = 0.f;
    f32x16 Of0 = {}, Of1 = {};

    // staging: 512 threads cover 64 rows x 8 granules, ONE uint4 per matrix
    const int sr = tid >> 3, c0 = tid & 7;
    const unsigned short* kg = k    + ((long)bh * S_LEN + sr) * HD + c0 * 8;
    const unsigned short* vg = vt_g + ((long)bh * HD + sr) * S_LEN + c0 * 8;
    const int wof = sr * STK + c0 * 8;

    // prologue: tile 0 -> buf0; tile 1 -> regs
    uint4 rk = *(const uint4*)(kg);
    uint4 rv = *(const uint4*)(vg);
    float rmv = 0.f;
    if (tid < 64) rmv = (mask[b * S_LEN + tid] == 0) ? -1e9f : 0.f;
    *(uint4*)&kt[0][wof] = rk;
    *(uint4*)&vt[0][wof] = rv;
    if (tid < 64) mkv[0][tid] = rmv;
    rk = *(const uint4*)(kg + (long)64 * HD);
    rv = *(const uint4*)(vg + 64);
    if (tid < 64) rmv = (mask[b * S_LEN + 64 + tid] == 0) ? -1e9f : 0.f;
    asm volatile("s_waitcnt lgkmcnt(0)" ::: "memory");
    __builtin_amdgcn_s_barrier();
    asm volatile("" ::: "memory");

    for (int k0 = 0; k0 < S_LEN; k0 += 64) {
        const int cur = (k0 >> 6) & 1;
        // write tile t+1 into the other buffer; issue tile t+2 global loads
        if (k0 + 64 < S_LEN) {
            *(uint4*)&kt[cur ^ 1][wof] = rk;
            *(uint4*)&vt[cur ^ 1][wof] = rv;
            if (tid < 64) mkv[cur ^ 1][tid] = rmv;
            if (k0 + 128 < S_LEN) {
                rk = *(const uint4*)(kg + (long)(k0 + 128) * HD);
                rv = *(const uint4*)(vg + (k0 + 128));
                if (tid < 64) rmv = (mask[b * S_LEN + k0 + 128 + tid] == 0) ? -1e9f : 0.f;
            }
        }

        // QK^T (swapped) over MY key group: S = K·Q^T -> D[key][q], q=lane&31,
        // key = 32p + 8*(r>>2) + 4*hi + (r&3). Mask in the C-init (exact:
        // result = mask + sum of products, same as post-add).
        float st[16];
        __builtin_amdgcn_s_setprio(1);
        {
            f32x16 s;
#pragma unroll
            for (int m = 0; m < 4; m++) {
                const float4 mv = *(const float4*)&mkv[cur][p * 32 + m * 8 + hi * 4];
                s[4 * m + 0] = mv.x; s[4 * m + 1] = mv.y;
                s[4 * m + 2] = mv.z; s[4 * m + 3] = mv.w;
            }
#pragma unroll
            for (int t = 0; t < 4; t++) {
                bf16x8 kf = *(const bf16x8*)
                    &kt[cur][(p * 32 + ar) * STK + (2 * t + hi) * 8];
                s = __builtin_amdgcn_mfma_f32_32x32x16_bf16(kf, qu[t].v, s, 0, 0, 0);
            }
            __builtin_amdgcn_s_setprio(0);
#pragma unroll
            for (int r = 0; r < 16; r++) st[r] = s[r];
        }

        // per-lane max tree, then PAIR-combine (lane l <-> l+32 share a q-row)
        float pmax = fmaxf(fmaxf(fmaxf(st[0], st[1]), fmaxf(st[2], st[3])),
                     fmaxf(fmaxf(st[4], st[5]), fmaxf(st[6], st[7])));
        pmax = fmaxf(pmax,
                fmaxf(fmaxf(fmaxf(st[8], st[9]), fmaxf(st[10], st[11])),
                      fmaxf(fmaxf(st[12], st[13]), fmaxf(st[14], st[15]))));
        pmax = pair_max(pmax);   // row max within my key group, pair-consistent

        // defer-max: rescale only when some row's max grew by > 8 (log2)
        if (__any(pmax > mrun + 8.f)) {
            const float mn = fmaxf(mrun, pmax);
            const float alpha = exp2_hw(mrun - mn);
            Of0 *= alpha; Of1 *= alpha; lsum *= alpha;
            mrun = mn;
        }

        // P = exp2(st - mrun); per-lane partial row-sum; pack to bf16 pairs
        float pr[16];
        float ls = 0.f;
#pragma unroll
        for (int r = 0; r < 16; r++) {
            pr[r] = exp2_hw(st[r] - mrun);
            ls += pr[r];
        }
        lsum += ls;
        unsigned wa[4], wb[4];
#pragma unroll
        for (int m = 0; m < 4; m++) {
            wa[m] = pk2(pr[4 * m + 0], pr[4 * m + 1]);
            wb[m] = pk2(pr[4 * m + 2], pr[4 * m + 3]);
        }

        // PV B-fragments in-register (T12): local fragment s5l (keys
        // 16*(2p+s5l)..+15) uses rows m' = 2*s5l + hi_c:
        // pl32swap(wa[mp], wa[mp+1]) delivers (u[0], u[2]) for BOTH halves.
        union { unsigned u[4]; bf16x8 v; } F[2];
#pragma unroll
        for (int s5 = 0; s5 < 2; s5++) {
            const int mp = s5 * 2;
            unsigned f0 = wa[mp], f2 = wa[mp + 1];
            unsigned f1 = wb[mp], f3 = wb[mp + 1];
            pl32swap(f0, f2);
            pl32swap(f1, f3);
            F[s5].u[0] = f0; F[s5].u[1] = f1; F[s5].u[2] = f2; F[s5].u[3] = f3;
        }

        // PV: O += V^T · P -> D[d][q]; A-frag = V^T[32g + ar][key-slice 2p+s5]
        __builtin_amdgcn_s_setprio(1);
#pragma unroll
        for (int s5 = 0; s5 < 2; s5++) {
            const int gr = (2 * (2 * p + s5) + hi) * 8;
            bf16x8 vf0 = *(const bf16x8*)&vt[cur][(0 * 32 + ar) * STK + gr];
            Of0 = __builtin_amdgcn_mfma_f32_32x32x16_bf16(vf0, F[s5].v, Of0, 0, 0, 0);
            bf16x8 vf1 = *(const bf16x8*)&vt[cur][(1 * 32 + ar) * STK + gr];
            Of1 = __builtin_amdgcn_mfma_f32_32x32x16_bf16(vf1, F[s5].v, Of1, 0, 0, 0);
        }
        __builtin_amdgcn_s_setprio(0);

        // one barrier per tile (lgkm-only; global prefetch stays in flight)
        asm volatile("s_waitcnt lgkmcnt(0)" ::: "memory");
        __builtin_amdgcn_s_barrier();
        asm volatile("" ::: "memory");
    }

    // ---- parity merge: flash-combine (O,m,l) of p=0 and p=1 waves ----
    // Overlay the dead staging LDS: kt <- Of0 partials (4096 f32),
    // vt <- Of1 partials (4096 f32) + [m,l] (512 f32). XOR on the m-index
    // keeps writes/reads at the bank floor.
    const float lp = pair_sum(lsum);           // row sum within my key group
    float* mo0 = (float*)&kt[0][0];
    float* mo1 = (float*)&vt[0][0];
    float* mml = (float*)&vt[0][0] + 4096;
    const int mbase = (chunk * 64 + lane) * 16;
    const int mx4 = (lane >> 1) & 3;
    if (p == 1) {
#pragma unroll
        for (int m = 0; m < 4; m++) {
            const int off = mbase + ((m ^ mx4) << 2);
            *(float4*)&mo0[off] = make_float4(Of0[4*m+0], Of0[4*m+1], Of0[4*m+2], Of0[4*m+3]);
            *(float4*)&mo1[off] = make_float4(Of1[4*m+0], Of1[4*m+1], Of1[4*m+2], Of1[4*m+3]);
        }
        mml[(chunk * 64 + lane) * 2 + 0] = mrun;
        mml[(chunk * 64 + lane) * 2 + 1] = lp;
    }
    __syncthreads();
    if (p == 0) {
        const float m1 = mml[(chunk * 64 + lane) * 2 + 0];
        const float l1 = mml[(chunk * 64 + lane) * 2 + 1];
        const float mm = fmaxf(mrun, m1);
        const float a0 = exp2_hw(mrun - mm);
        const float a1 = exp2_hw(m1 - mm);
        const float inv = 1.f / (lp * a0 + l1 * a1);
        // d = 32g + 8m + 4hi + (0..3)
        unsigned short* cb = ctx + ((long)b * S_LEN + sq) * HID + h * HD;
#pragma unroll
        for (int m = 0; m < 4; m++) {
            const int off = mbase + ((m ^ mx4) << 2);
            const float4 p0 = *(const float4*)&mo0[off];
            const float4 p1 = *(const float4*)&mo1[off];
            uint2 o0, o1;
            o0.x = pk2((Of0[4*m+0] * a0 + p0.x * a1) * inv,
                       (Of0[4*m+1] * a0 + p0.y * a1) * inv);
            o0.y = pk2((Of0[4*m+2] * a0 + p0.z * a1) * inv,
                       (Of0[4*m+3] * a0 + p0.w * a1) * inv);
            *(uint2*)&cb[m * 8 + hi * 4] = o0;
            o1.x = pk2((Of1[4*m+0] * a0 + p1.x * a1) * inv,
                       (Of1[4*m+1] * a0 + p1.y * a1) * inv);
            o1.y = pk2((Of1[4*m+2] * a0 + p1.z * a1) * inv,
                       (Of1[4*m+3] * a0 + p1.w * a1) * inv);
            *(uint2*)&cb[32 + m * 8 + hi * 4] = o1;
        }
    }
}

extern "C" void kernel_launch(void* const* d_in, const int* in_sizes, int n_in,
                              void* d_out, int out_size, void* d_ws, size_t ws_size,
                              hipStream_t stream) {
    float* outp = (float*)d_out;

    const float* x = nullptr; const int* mask = nullptr;
    const float* qkv_w = nullptr; const float* qkv_b = nullptr;
    const float* out_w = nullptr; const float* out_b = nullptr;
    for (int i = 0; i < n_in; i++) {
        switch (in_sizes[i]) {
            case 4194304: x     = (const float*)d_in[i]; break;
            case 4096:    mask  = (const int*)d_in[i];   break;
            case 3145728: qkv_w = (const float*)d_in[i]; break;
            case 3072:    qkv_b = (const float*)d_in[i]; break;
            case 1048576: out_w = (const float*)d_in[i]; break;
            case 1024:    out_b = (const float*)d_in[i]; break;
            default: break;
        }
    }
    if (!x || !mask || !qkv_w || !qkv_b || !out_w || !out_b) {
        fill_constf<<<256, 256, 0, stream>>>(outp, (long)out_size, 1000.0f);
        return;
    }

    const size_t per = (size_t)BATCH * NH * S_LEN * HD;   // 4,194,304
    const size_t nx  = (size_t)BATCH * S_LEN * HID;
    const size_t nqw = (size_t)3 * HID * HID;
    const size_t now = (size_t)HID * HID;
    if (ws_size < 4 * per * sizeof(unsigned short)) {
        fill_constf<<<256, 256, 0, stream>>>(outp, (long)out_size, 2000.0f);
        return;
    }

    // Aliasing discipline (no buffer read+written in the same kernel):
    //   xb  = wsc : dead after gemm1; attn overwrites with ctx
    //   qwb = d_out[0,6.3MB) : dead after gemm1; gemm2 overwrites with output
    //   owb = wsq : written AFTER attn (q dead), read only by gemm2
    unsigned short* wsq = (unsigned short*)d_ws;
    unsigned short* wsk = wsq + per;
    unsigned short* wsv = wsk + per;               // V^T [b,h,64,S]
    unsigned short* wsc = wsv + per;               // phase 1: xb; phase 2: ctx
    unsigned short* xb  = wsc;
    unsigned short* qwb = (unsigned short*)d_out;
    unsigned short* owb = wsq;

    cvt2_bf16<<<1024, 256, 0, stream>>>(x, xb, (long)(nx / 8), qkv_w, qwb, (long)(nqw / 8));
    gemm_bf16<<<dim3(3 * HID / 128, BATCH * S_LEN / 128), 256, 0, stream>>>(
        xb, qwb, qkv_b, wsq, wsk, wsv, nullptr, 0);
    attn<<<dim3(S_LEN / 128, NH, BATCH), 512, 0, stream>>>(wsq, wsk, wsv, mask, wsc);
    cvt_bf16<<<512, 256, 0, stream>>>(out_w, owb, (long)(now / 8));
    gemm_out64<<<dim3(HID / 64, BATCH * S_LEN / 128), 256, 0, stream>>>(
        wsc, owb, out_b, outp);
}